// Round 5
// baseline (428.815 us; speedup 1.0000x reference)
//
#include <hip/hip_runtime.h>

#define S_LEN 16
#define NMODEL 4096
#define DHEAD 128
#define HHEADS 32
#define MCACHE 8192
#define SPLITK 32
#define KSLICE (NMODEL / SPLITK)   // 128
#define CHUNK 64
#define NCHUNK (MCACHE / CHUNK)    // 128
#define SCPAD 17                   // odd stride -> conflict-free column reads

// ---------------- Kernel 1: split-K partial QKV projection ----------------
// grid (8, 32, 3) = 768 blocks, block 256. 64-VGPR cap -> 8 waves/SIMD.
__global__ __launch_bounds__(256, 8) void qkv_gemm(const float* __restrict__ X,
                                                   const float* __restrict__ Wq,
                                                   const float* __restrict__ Wk,
                                                   const float* __restrict__ Wv,
                                                   float* __restrict__ part) {
    const int tid   = threadIdx.x;
    const int col2  = blockIdx.x * 256 + tid;
    const int split = blockIdx.y;
    const int mat   = blockIdx.z;
    const float* __restrict__ W = (mat == 0) ? Wq : (mat == 1) ? Wk : Wv;
    const int k0 = split * KSLICE;

    __shared__ float Xs[KSLICE][S_LEN];     // 8 KB
    for (int i = tid; i < KSLICE * S_LEN; i += 256) {
        const int s = i & 15, k = i >> 4;
        Xs[k][s] = X[s * NMODEL + k0 + k];
    }
    __syncthreads();

    float2 acc[S_LEN];
#pragma unroll
    for (int s = 0; s < S_LEN; ++s) { acc[s].x = 0.f; acc[s].y = 0.f; }

    const float2* __restrict__ Wp = (const float2*)(W + (size_t)k0 * NMODEL) + col2;

#pragma unroll 8
    for (int k = 0; k < KSLICE; ++k) {
        const float2 w = Wp[(size_t)k * (NMODEL / 2)];
        const float4* __restrict__ xr = (const float4*)&Xs[k][0];
#pragma unroll
        for (int s4 = 0; s4 < 4; ++s4) {
            const float4 xv = xr[s4];
            acc[s4 * 4 + 0].x += xv.x * w.x;  acc[s4 * 4 + 0].y += xv.x * w.y;
            acc[s4 * 4 + 1].x += xv.y * w.x;  acc[s4 * 4 + 1].y += xv.y * w.y;
            acc[s4 * 4 + 2].x += xv.z * w.x;  acc[s4 * 4 + 2].y += xv.z * w.y;
            acc[s4 * 4 + 3].x += xv.w * w.x;  acc[s4 * 4 + 3].y += xv.w * w.y;
        }
    }

    float2* __restrict__ pp =
        (float2*)(part + (size_t)(mat * SPLITK + split) * S_LEN * NMODEL) + col2;
#pragma unroll
    for (int s = 0; s < S_LEN; ++s) pp[(size_t)s * (NMODEL / 2)] = acc[s];
}

// ---------------- Kernel 2: reduce split-K partials ----------------
__global__ __launch_bounds__(256) void qkv_reduce(const float* __restrict__ part,
                                                  float* __restrict__ qkv) {
    const int i4   = blockIdx.x * 256 + threadIdx.x;
    const int flat = i4 * 4;
    const int mat  = flat / (S_LEN * NMODEL);
    const int rem  = flat % (S_LEN * NMODEL);
    float4 sum = {0.f, 0.f, 0.f, 0.f};
#pragma unroll 8
    for (int sp = 0; sp < SPLITK; ++sp) {
        const float4 v = *(const float4*)(part +
            (size_t)(mat * SPLITK + sp) * (S_LEN * NMODEL) + rem);
        sum.x += v.x; sum.y += v.y; sum.z += v.z; sum.w += v.w;
    }
    *(float4*)(qkv + flat) = sum;
}

// ---------------- Kernel 3: flash-decode partial attention ----------------
// grid = (NCHUNK=128, HHEADS=32), block = 256 (4 waves), 64 rows/block.
// 64-VGPR cap -> 8 waves/SIMD.
__global__ __launch_bounds__(256, 8) void attn_partial(const float* __restrict__ qkv,
                                                       const float* __restrict__ cacheK,
                                                       const float* __restrict__ cacheV,
                                                       const int* __restrict__ Pp,
                                                       float* __restrict__ opart,
                                                       float* __restrict__ mstat,
                                                       float* __restrict__ lstat) {
    const int c   = blockIdx.x;
    const int h   = blockIdx.y;
    const int tid = threadIdx.x;
    const int P   = *Pp;

    const float* qb = qkv;
    const float* kb = qkv + S_LEN * NMODEL;
    const float* vb = qkv + 2 * S_LEN * NMODEL;

    __shared__ float q_s[S_LEN][DHEAD];      // 8 KB
    __shared__ float sc[CHUNK][SCPAD];       // 4.3 KB
    __shared__ float mloc[S_LEN], lloc[S_LEN];

    for (int i = tid; i < S_LEN * DHEAD; i += 256)
        q_s[i >> 7][i & 127] = qb[(i >> 7) * NMODEL + h * DHEAD + (i & 127)];
    __syncthreads();

    // ---- phase 1: scores (one row per thread-quad; packed wave loads) ----
    {
        const int sub = tid & 3;             // owns dims j*16 + sub*4 .. +3
        const int r   = tid >> 2;            // row 0..63
        const int gm  = c * CHUNK + r;
        const float* kr = (gm >= P && gm < P + S_LEN)
            ? kb + (size_t)(gm - P) * NMODEL + h * DHEAD       // virtual cache write
            : cacheK + ((size_t)h * MCACHE + gm) * DHEAD;

        float acc[S_LEN];
#pragma unroll
        for (int s = 0; s < S_LEN; ++s) acc[s] = 0.f;

#pragma unroll
        for (int j = 0; j < 8; ++j) {
            const float4 kv = *(const float4*)(kr + j * 16 + sub * 4);
#pragma unroll
            for (int s = 0; s < S_LEN; ++s) {
                const float4 qv = *(const float4*)&q_s[s][j * 16 + sub * 4];
                acc[s] += kv.x * qv.x + kv.y * qv.y + kv.z * qv.z + kv.w * qv.w;
            }
        }
#pragma unroll
        for (int s = 0; s < S_LEN; ++s) {
            float v = acc[s];
            v += __shfl_xor(v, 1, 64);
            v += __shfl_xor(v, 2, 64);
            acc[s] = v;
        }
        if (sub == 0) {
#pragma unroll
            for (int s = 0; s < S_LEN; ++s) sc[r][s] = acc[s];
        }
    }
    __syncthreads();

    // ---- phase 2: per-s max & sumexp (64 rows == 64 lanes) ----
    {
        const int wv = tid >> 6, lane = tid & 63;
#pragma unroll
        for (int si = 0; si < 4; ++si) {
            const int s = wv * 4 + si;
            float v  = sc[lane][s];
            float mx = v;
            for (int off = 32; off > 0; off >>= 1) mx = fmaxf(mx, __shfl_xor(mx, off, 64));
            const float e = __expf(v - mx);
            sc[lane][s] = e;
            float sum = e;
            for (int off = 32; off > 0; off >>= 1) sum += __shfl_xor(sum, off, 64);
            if (lane == 0) { mloc[s] = mx; lloc[s] = sum; }
        }
    }
    __syncthreads();

    // ---- phase 3: o[s][d] = sum_m p*V ; unrolled x2, loads staged ----
    {
        const int s  = tid >> 4;
        const int d0 = (tid & 15) * 8;
        float a[8];
#pragma unroll
        for (int j = 0; j < 8; ++j) a[j] = 0.f;

        for (int m = 0; m < CHUNK; m += 2) {
            const int gm0 = c * CHUNK + m;
            const int gm1 = gm0 + 1;
            const float* vr0 = (gm0 >= P && gm0 < P + S_LEN)
                ? vb + (size_t)(gm0 - P) * NMODEL + h * DHEAD
                : cacheV + ((size_t)h * MCACHE + gm0) * DHEAD;
            const float* vr1 = (gm1 >= P && gm1 < P + S_LEN)
                ? vb + (size_t)(gm1 - P) * NMODEL + h * DHEAD
                : cacheV + ((size_t)h * MCACHE + gm1) * DHEAD;
            const float4 v00 = *(const float4*)(vr0 + d0);
            const float4 v01 = *(const float4*)(vr0 + d0 + 4);
            const float4 v10 = *(const float4*)(vr1 + d0);
            const float4 v11 = *(const float4*)(vr1 + d0 + 4);
            const float p0 = sc[m][s];
            const float p1 = sc[m + 1][s];
            a[0] += p0 * v00.x; a[1] += p0 * v00.y; a[2] += p0 * v00.z; a[3] += p0 * v00.w;
            a[4] += p0 * v01.x; a[5] += p0 * v01.y; a[6] += p0 * v01.z; a[7] += p0 * v01.w;
            a[0] += p1 * v10.x; a[1] += p1 * v10.y; a[2] += p1 * v10.z; a[3] += p1 * v10.w;
            a[4] += p1 * v11.x; a[5] += p1 * v11.y; a[6] += p1 * v11.z; a[7] += p1 * v11.w;
        }
        const size_t ob = (((size_t)h * NCHUNK + c) * S_LEN + s) * DHEAD + d0;
        float4 w0; w0.x = a[0]; w0.y = a[1]; w0.z = a[2]; w0.w = a[3];
        float4 w1; w1.x = a[4]; w1.y = a[5]; w1.z = a[6]; w1.w = a[7];
        *(float4*)(opart + ob)     = w0;
        *(float4*)(opart + ob + 4) = w1;
    }
    if (tid < S_LEN) {
        mstat[((size_t)h * NCHUNK + c) * S_LEN + tid] = mloc[tid];
        lstat[((size_t)h * NCHUNK + c) * S_LEN + tid] = lloc[tid];
    }
}

// ---------------- Kernel 4: combine chunk partials ----------------
__global__ __launch_bounds__(128) void attn_combine(const float* __restrict__ opart,
                                                    const float* __restrict__ mstat,
                                                    const float* __restrict__ lstat,
                                                    float* __restrict__ out) {
    const int d = threadIdx.x;
    const int s = blockIdx.x;
    const int h = blockIdx.y;

    float gmax = -1e30f;
#pragma unroll 8
    for (int c = 0; c < NCHUNK; ++c)
        gmax = fmaxf(gmax, mstat[((size_t)h * NCHUNK + c) * S_LEN + s]);

    float L = 0.f, o = 0.f;
#pragma unroll 4
    for (int c = 0; c < NCHUNK; ++c) {
        const size_t si = (size_t)h * NCHUNK * S_LEN + (size_t)c * S_LEN + s;
        const float w = __expf(mstat[si] - gmax);
        L += lstat[si] * w;
        o += w * opart[si * DHEAD + d];
    }
    out[((size_t)h * S_LEN + s) * DHEAD + d] = o / L;
}

extern "C" void kernel_launch(void* const* d_in, const int* in_sizes, int n_in,
                              void* d_out, int out_size, void* d_ws, size_t ws_size,
                              hipStream_t stream) {
    const float* X      = (const float*)d_in[0];
    const float* Wq     = (const float*)d_in[1];
    const float* Wk     = (const float*)d_in[2];
    const float* Wv     = (const float*)d_in[3];
    const float* cacheK = (const float*)d_in[4];
    const float* cacheV = (const float*)d_in[5];
    const int*   P      = (const int*)d_in[6];
    float* out = (float*)d_out;
    float* ws  = (float*)d_ws;

    // ws layout (floats). opart aliases part (dead after qkv_reduce);
    // region size = max(part = 3*32*16*4096 = 6.29M, opart = 8.39M) = 8.39M.
    float* qkv   = ws;                                   // 196608
    float* part  = qkv + 3 * S_LEN * NMODEL;
    float* opart = part;
    float* mstat = opart + (size_t)HHEADS * NCHUNK * S_LEN * DHEAD;
    float* lstat = mstat + (size_t)HHEADS * NCHUNK * S_LEN;

    qkv_gemm<<<dim3(8, SPLITK, 3), 256, 0, stream>>>(X, Wq, Wk, Wv, part);
    qkv_reduce<<<(3 * S_LEN * NMODEL / 4) / 256, 256, 0, stream>>>(part, qkv);
    attn_partial<<<dim3(NCHUNK, HHEADS), 256, 0, stream>>>(qkv, cacheK, cacheV, P,
                                                           opart, mstat, lstat);
    attn_combine<<<dim3(S_LEN, HHEADS), DHEAD, 0, stream>>>(opart, mstat, lstat, out);
}